// Round 1
// baseline (447.169 us; speedup 1.0000x reference)
//
#include <hip/hip_runtime.h>
#include <hip/hip_bf16.h>

// LocallyConnected2d: B=16, C=32, O=32, H=W=64, K=3x3, pad=1, stride=1.
// out[b,o,h,w] = sum_{c,k} x[b,c,h+dh,w+dw] * weight[o,c,h,w,k]
// Memory-bound: weight = 151 MB read once; batch loop inside thread so each
// weight element is reused 16x from registers.

#define BATCH 16
#define CIN   32
#define OCH   32
#define HH    64
#define WW    64

__global__ __launch_bounds__(256)
void lc2d_kernel(const float* __restrict__ x,
                 const float* __restrict__ wt,
                 float* __restrict__ out) {
    const int w = threadIdx.x;                    // 0..63, lane == w
    const int h = blockIdx.x * 4 + threadIdx.y;   // 0..63, wave-uniform
    const int o = blockIdx.y;                     // 0..31

    float acc[BATCH];
#pragma unroll
    for (int b = 0; b < BATCH; ++b) acc[b] = 0.f;

    // weight[o][c][h][w][k]
    const int wt_oh = ((o * CIN) * HH + h) * WW + w;   // advances by HH*WW per c

    for (int c = 0; c < CIN; ++c) {
        const float* wp = wt + (wt_oh + c * (HH * WW)) * 9;
        float wk[9];
#pragma unroll
        for (int k = 0; k < 9; ++k) wk[k] = wp[k];

        const int xc = c * (HH * WW);
#pragma unroll
        for (int b = 0; b < BATCH; ++b) {
            const float* xp = x + (b * CIN) * (HH * WW) + xc;
#pragma unroll
            for (int dh = -1; dh <= 1; ++dh) {
                const int ih = h + dh;               // wave-uniform branch
                if (ih < 0 || ih >= HH) continue;
                const float* xrow = xp + ih * WW;
                // dw = -1, 0, +1 ; per-lane bounds only at w==0 / w==63
                const float xl = (w >= 1)      ? xrow[w - 1] : 0.f;
                const float xm =                 xrow[w];
                const float xr = (w <= WW - 2) ? xrow[w + 1] : 0.f;
                const int kb = (dh + 1) * 3;
                acc[b] = fmaf(xl, wk[kb + 0], acc[b]);
                acc[b] = fmaf(xm, wk[kb + 1], acc[b]);
                acc[b] = fmaf(xr, wk[kb + 2], acc[b]);
            }
        }
    }

#pragma unroll
    for (int b = 0; b < BATCH; ++b) {
        out[((b * OCH + o) * HH + h) * WW + w] = acc[b];
    }
}

extern "C" void kernel_launch(void* const* d_in, const int* in_sizes, int n_in,
                              void* d_out, int out_size, void* d_ws, size_t ws_size,
                              hipStream_t stream) {
    const float* x  = (const float*)d_in[0];
    const float* wt = (const float*)d_in[1];
    float* out = (float*)d_out;

    dim3 block(64, 4);
    dim3 grid(HH / 4, OCH);   // 16 x 32 = 512 blocks
    lc2d_kernel<<<grid, block, 0, stream>>>(x, wt, out);
}

// Round 2
// 107.022 us; speedup vs baseline: 4.1783x; 4.1783x over previous
//
#include <hip/hip_runtime.h>
#include <hip/hip_bf16.h>

// LocallyConnected2d: B=16, C=32, O=32, H=W=64, K=3x3, pad=1, stride=1.
// out[b,o,h,w] = sum_{c,k} x[b,c,h+dh,w+dw] * weight[o,c,h,w,k]
//
// R2: branch-free inner loop (edge masks folded into the 9 weights once per
// c), batch split 2x across blocks (8 acc regs each; 2nd weight read hits
// L3), float4 weight loads. Goal: kill the R1 scratch spill (VGPR=20 ->
// runtime-indexed acc[] in local memory).

#define BATCH 16
#define BB    8     // batches per block
#define CIN   32
#define OCH   32
#define HH    64
#define WW    64

typedef float f32x4 __attribute__((ext_vector_type(4), aligned(4)));

__global__ __launch_bounds__(256)
void lc2d_kernel(const float* __restrict__ x,
                 const float* __restrict__ wt,
                 float* __restrict__ out) {
    const int w  = threadIdx.x;                       // 0..63, lane == w
    const int h  = (blockIdx.x >> 1) * 4 + threadIdx.y;
    const int bz = blockIdx.x & 1;                    // batch half
    const int o  = blockIdx.y;
    const int b0 = bz * BB;

    // Boundary handling: clamp indices (always in-bounds loads) and zero the
    // corresponding weights once per c. Inner loop is then branch-free.
    const float mt = (h > 0)      ? 1.f : 0.f;
    const float mb = (h < HH - 1) ? 1.f : 0.f;
    const float ml = (w > 0)      ? 1.f : 0.f;
    const float mr = (w < WW - 1) ? 1.f : 0.f;
    const int iht = (h > 0)      ? h - 1 : 0;
    const int ihb = (h < HH - 1) ? h + 1 : HH - 1;
    const int iwl = (w > 0)      ? w - 1 : 0;
    const int iwr = (w < WW - 1) ? w + 1 : WW - 1;

    float acc[BB];
#pragma unroll
    for (int b = 0; b < BB; ++b) acc[b] = 0.f;

    // weight[o][c][h][w][k]; per-c stride = HH*WW*9 floats
    const float* wp = wt + (size_t)(((o * CIN) * HH + h) * WW + w) * 9;

    for (int c = 0; c < CIN; ++c) {
        const float* wpc = wp + c * (HH * WW * 9);
        f32x4 w03 = *(const f32x4*)(wpc + 0);
        f32x4 w47 = *(const f32x4*)(wpc + 4);
        float w8  = wpc[8];

        float wk0 = w03.x * (mt * ml);
        float wk1 = w03.y * mt;
        float wk2 = w03.z * (mt * mr);
        float wk3 = w03.w * ml;
        float wk4 = w47.x;
        float wk5 = w47.y * mr;
        float wk6 = w47.z * (mb * ml);
        float wk7 = w47.w * mb;
        float wk8 = w8    * (mb * mr);

        const float* xc = x + (size_t)(b0 * CIN + c) * (HH * WW);
#pragma unroll
        for (int b = 0; b < BB; ++b) {
            const float* xb = xc + (size_t)b * (CIN * HH * WW);
            const float* r0 = xb + iht * WW;
            const float* r1 = xb + h   * WW;
            const float* r2 = xb + ihb * WW;
            float a = acc[b];
            a = fmaf(r0[iwl], wk0, a);
            a = fmaf(r0[w],   wk1, a);
            a = fmaf(r0[iwr], wk2, a);
            a = fmaf(r1[iwl], wk3, a);
            a = fmaf(r1[w],   wk4, a);
            a = fmaf(r1[iwr], wk5, a);
            a = fmaf(r2[iwl], wk6, a);
            a = fmaf(r2[w],   wk7, a);
            a = fmaf(r2[iwr], wk8, a);
            acc[b] = a;
        }
    }

#pragma unroll
    for (int b = 0; b < BB; ++b) {
        out[(size_t)(((b0 + b) * OCH + o) * HH + h) * WW + w] = acc[b];
    }
}

extern "C" void kernel_launch(void* const* d_in, const int* in_sizes, int n_in,
                              void* d_out, int out_size, void* d_ws, size_t ws_size,
                              hipStream_t stream) {
    const float* x  = (const float*)d_in[0];
    const float* wt = (const float*)d_in[1];
    float* out = (float*)d_out;

    dim3 block(64, 4);
    dim3 grid((HH / 4) * 2, OCH);   // 32 x 32 = 1024 blocks (h-tile x batch-half, o)
    lc2d_kernel<<<grid, block, 0, stream>>>(x, wt, out);
}

// Round 3
// 59.198 us; speedup vs baseline: 7.5538x; 1.8079x over previous
//
#include <hip/hip_runtime.h>
#include <hip/hip_bf16.h>

// LocallyConnected2d: B=16, C=32, O=32, H=W=64, K=3x3, pad=1, stride=1.
// out[b,o,h,w] = sum_{c,k} x[b,c,h+dh,w+dw] * weight[o,c,h,w,k]
//
// R3: issue-efficiency restructure.
//  - lane = w; horizontal taps via ds_bpermute (lane+-1) instead of 3x reload
//  - OO=2 output channels per thread (acc[16]): FMA:VMEM ~144:30 per c-iter
//  - c-split x2 across blocks + f32 atomicAdd (2 commutative addends ->
//    deterministic); d_out zeroed via hipMemsetAsync
//  - next-c weight prefetch into registers to cover L3/HBM latency

#define CIN  32
#define OCH  32
#define HH   64
#define WW   64
#define BB   8    // batches per thread
#define OO   2    // output channels per thread
#define CC   16   // input channels per block (c-split 2)

typedef float f32x4 __attribute__((ext_vector_type(4), aligned(4)));

__device__ __forceinline__ float lane_pick(int byte_addr, float v) {
    return __int_as_float(__builtin_amdgcn_ds_bpermute(byte_addr, __float_as_int(v)));
}

__global__ __launch_bounds__(256)
void lc2d_kernel(const float* __restrict__ x,
                 const float* __restrict__ wt,
                 float* __restrict__ out) {
    const int w  = threadIdx.x;                 // 0..63, lane == w
    const int h  = blockIdx.x * 4 + threadIdx.y;
    const int og = blockIdx.y;                  // 0..15
    const int bz = blockIdx.z & 1;              // batch half
    const int cg = blockIdx.z >> 1;             // c half
    const int o0 = og * OO;
    const int b0 = bz * BB;
    const int c0 = cg * CC;

    // edge masks (folded into weights); clamped row indices keep loads legal
    const float mt = (h > 0)      ? 1.f : 0.f;
    const float mb = (h < HH - 1) ? 1.f : 0.f;
    const float ml = (w > 0)      ? 1.f : 0.f;
    const float mr = (w < WW - 1) ? 1.f : 0.f;
    const int iht = (h > 0)      ? h - 1 : 0;
    const int ihb = (h < HH - 1) ? h + 1 : HH - 1;

    // bpermute byte addresses for lane w-1 / w+1 (clamped; garbage edges are
    // multiplied by zeroed weights anyway)
    const int lup = ((w > 0)  ? w - 1 : 0)  << 2;
    const int ldn = ((w < 63) ? w + 1 : 63) << 2;

    float acc[OO * BB];
#pragma unroll
    for (int i = 0; i < OO * BB; ++i) acc[i] = 0.f;

    const size_t WSTRC = (size_t)HH * WW * 9;     // per-c weight stride (floats)
    const size_t WSTRO = (size_t)CIN * WSTRC;     // per-o weight stride
    const float* wpa = wt + (size_t)o0 * WSTRO + (size_t)c0 * WSTRC
                          + ((size_t)h * WW + w) * 9;
    const float* wpb = wpa + WSTRO;

    const float* xb0 = x + ((size_t)b0 * CIN + c0) * (HH * WW);
    const int ro_t = iht * WW + w;
    const int ro_m = h   * WW + w;
    const int ro_b = ihb * WW + w;

    // preload c=0 weights for both o's
    f32x4 a03 = *(const f32x4*)(wpa);
    f32x4 a47 = *(const f32x4*)(wpa + 4);
    float a8  = wpa[8];
    f32x4 b03 = *(const f32x4*)(wpb);
    f32x4 b47 = *(const f32x4*)(wpb + 4);
    float b8  = wpb[8];

    for (int c = 0; c < CC; ++c) {
        // fold edge masks into current weights
        const float wa0 = a03.x * (mt * ml), wa1 = a03.y * mt, wa2 = a03.z * (mt * mr);
        const float wa3 = a03.w * ml,        wa4 = a47.x,      wa5 = a47.y * mr;
        const float wa6 = a47.z * (mb * ml), wa7 = a47.w * mb, wa8 = a8 * (mb * mr);
        const float wb0 = b03.x * (mt * ml), wb1 = b03.y * mt, wb2 = b03.z * (mt * mr);
        const float wb3 = b03.w * ml,        wb4 = b47.x,      wb5 = b47.y * mr;
        const float wb6 = b47.z * (mb * ml), wb7 = b47.w * mb, wb8 = b8 * (mb * mr);

        // prefetch next-c weights (flight time covered by the b-loop below)
        const int cn = (c + 1 < CC) ? c + 1 : c;
        const float* npa = wpa + (size_t)cn * WSTRC;
        const float* npb = wpb + (size_t)cn * WSTRC;
        a03 = *(const f32x4*)(npa);
        a47 = *(const f32x4*)(npa + 4);
        a8  = npa[8];
        b03 = *(const f32x4*)(npb);
        b47 = *(const f32x4*)(npb + 4);
        b8  = npb[8];

        const float* xc = xb0 + (size_t)c * (HH * WW);
#pragma unroll
        for (int b = 0; b < BB; ++b) {
            const float* xp = xc + (size_t)b * (CIN * HH * WW);
            const float xt = xp[ro_t];
            const float xm = xp[ro_m];
            const float xd = xp[ro_b];
            const float xtl = lane_pick(lup, xt), xtr = lane_pick(ldn, xt);
            const float xml = lane_pick(lup, xm), xmr = lane_pick(ldn, xm);
            const float xdl = lane_pick(lup, xd), xdr = lane_pick(ldn, xd);

            float a = acc[b];
            a = fmaf(xtl, wa0, a); a = fmaf(xt, wa1, a); a = fmaf(xtr, wa2, a);
            a = fmaf(xml, wa3, a); a = fmaf(xm, wa4, a); a = fmaf(xmr, wa5, a);
            a = fmaf(xdl, wa6, a); a = fmaf(xd, wa7, a); a = fmaf(xdr, wa8, a);
            acc[b] = a;

            float bq = acc[BB + b];
            bq = fmaf(xtl, wb0, bq); bq = fmaf(xt, wb1, bq); bq = fmaf(xtr, wb2, bq);
            bq = fmaf(xml, wb3, bq); bq = fmaf(xm, wb4, bq); bq = fmaf(xmr, wb5, bq);
            bq = fmaf(xdl, wb6, bq); bq = fmaf(xd, wb7, bq); bq = fmaf(xdr, wb8, bq);
            acc[BB + b] = bq;
        }
    }

#pragma unroll
    for (int b = 0; b < BB; ++b) {
#pragma unroll
        for (int oo = 0; oo < OO; ++oo) {
            atomicAdd(out + (((size_t)(b0 + b) * OCH + (o0 + oo)) * HH + h) * WW + w,
                      acc[oo * BB + b]);
        }
    }
}

extern "C" void kernel_launch(void* const* d_in, const int* in_sizes, int n_in,
                              void* d_out, int out_size, void* d_ws, size_t ws_size,
                              hipStream_t stream) {
    const float* x  = (const float*)d_in[0];
    const float* wt = (const float*)d_in[1];
    float* out = (float*)d_out;

    hipMemsetAsync(out, 0, (size_t)out_size * sizeof(float), stream);

    dim3 block(64, 4);
    dim3 grid(HH / 4, OCH / OO, 4);   // 16 x 16 x (2 batch-halves * 2 c-halves)
    lc2d_kernel<<<grid, block, 0, stream>>>(x, wt, out);
}